// Round 17
// baseline (77.058 us; speedup 1.0000x reference)
//
#include <hip/hip_runtime.h>

// Bahdanau additive attention, f32, 5 kernels.
// r16 + (a) proj reverted to r9's faster 128-thr 4x4 form (~5us measured),
// (b) scores: 1 q/block (4 blocks/CU), float4 acc chains, register softmax.
// B=8, TQ=128, TK=512, NIN=512, H=128, NV=512.

#define B_    8
#define TQ_   128
#define TK_   512
#define NIN_  512
#define H_    128
#define NV_   512
#define NQR   (B_*TQ_)           // 1024 query rows
#define NROWS (NQR + B_*TK_)     // 5120 projected rows
#define CTXN  (B_*TQ_*NV_)       // 524288 context elems

#define C2_   2.8853900817779268f   // 2*log2(e)
#define L2E_  1.4426950408889634f

__device__ __forceinline__ float fexp2(float x){ return __builtin_amdgcn_exp2f(x); }
__device__ __forceinline__ float frcp (float x){ return __builtin_amdgcn_rcpf(x); }

// ---------------------------------------------------------------- proj ----
// psum[s][row][h] = A[row, ks:ke) . W[h, ks:ke)
// 128 thr, tile 16 rows x 128 h, 4x4 microtile (16 FMA per 2 b128 reads),
// K-chunk 32, split-K=4 (kper=128). grid (320, 4) = 1280 blocks.
__global__ __launch_bounds__(128, 4) void proj_kernel(
        const float* __restrict__ query, const float* __restrict__ keys,
        const float* __restrict__ Wq, const float* __restrict__ Wk,
        float* __restrict__ psum, int kper) {
    __shared__ float at[32][20];
    __shared__ float wt[32][132];
    const int tid = threadIdx.x;
    const int r0  = blockIdx.x * 16;
    const float* in; const float* W;
    if (r0 < NQR) { in = query + (size_t)r0 * NIN_;         W = Wq; }
    else          { in = keys  + (size_t)(r0 - NQR) * NIN_; W = Wk; }

    const int r4 = (tid >> 5) * 4;       // 4 rows
    const int h4 = (tid & 31) * 4;       // 4 h
    const int sr  = tid >> 3;            // stage row 0..15
    const int skq = (tid & 7) * 4;       // stage k quad
    const int kb0 = blockIdx.y * kper;
    const int nc  = kper >> 5;

    const float* pA  = in + (size_t)sr * NIN_ + kb0 + skq;
    const float* pW0 = W + (size_t)(sr      ) * NIN_ + kb0 + skq;
    const float* pW1 = W + (size_t)(sr + 16 ) * NIN_ + kb0 + skq;
    const float* pW2 = W + (size_t)(sr + 32 ) * NIN_ + kb0 + skq;
    const float* pW3 = W + (size_t)(sr + 48 ) * NIN_ + kb0 + skq;
    const float* pW4 = W + (size_t)(sr + 64 ) * NIN_ + kb0 + skq;
    const float* pW5 = W + (size_t)(sr + 80 ) * NIN_ + kb0 + skq;
    const float* pW6 = W + (size_t)(sr + 96 ) * NIN_ + kb0 + skq;
    const float* pW7 = W + (size_t)(sr + 112) * NIN_ + kb0 + skq;

    float4 af = *(const float4*)pA;
    float4 w0 = *(const float4*)pW0, w1 = *(const float4*)pW1;
    float4 w2 = *(const float4*)pW2, w3 = *(const float4*)pW3;
    float4 w4 = *(const float4*)pW4, w5 = *(const float4*)pW5;
    float4 w6 = *(const float4*)pW6, w7 = *(const float4*)pW7;

    float acc[4][4];
#pragma unroll
    for (int i = 0; i < 4; ++i)
#pragma unroll
        for (int j = 0; j < 4; ++j) acc[i][j] = 0.0f;

    for (int c = 0; c < nc; ++c) {
        __syncthreads();
        at[skq+0][sr] = af.x; at[skq+1][sr] = af.y;
        at[skq+2][sr] = af.z; at[skq+3][sr] = af.w;
        wt[skq+0][sr    ] = w0.x; wt[skq+1][sr    ] = w0.y;
        wt[skq+2][sr    ] = w0.z; wt[skq+3][sr    ] = w0.w;
        wt[skq+0][sr+ 16] = w1.x; wt[skq+1][sr+ 16] = w1.y;
        wt[skq+2][sr+ 16] = w1.z; wt[skq+3][sr+ 16] = w1.w;
        wt[skq+0][sr+ 32] = w2.x; wt[skq+1][sr+ 32] = w2.y;
        wt[skq+2][sr+ 32] = w2.z; wt[skq+3][sr+ 32] = w2.w;
        wt[skq+0][sr+ 48] = w3.x; wt[skq+1][sr+ 48] = w3.y;
        wt[skq+2][sr+ 48] = w3.z; wt[skq+3][sr+ 48] = w3.w;
        wt[skq+0][sr+ 64] = w4.x; wt[skq+1][sr+ 64] = w4.y;
        wt[skq+2][sr+ 64] = w4.z; wt[skq+3][sr+ 64] = w4.w;
        wt[skq+0][sr+ 80] = w5.x; wt[skq+1][sr+ 80] = w5.y;
        wt[skq+2][sr+ 80] = w5.z; wt[skq+3][sr+ 80] = w5.w;
        wt[skq+0][sr+ 96] = w6.x; wt[skq+1][sr+ 96] = w6.y;
        wt[skq+2][sr+ 96] = w6.z; wt[skq+3][sr+ 96] = w6.w;
        wt[skq+0][sr+112] = w7.x; wt[skq+1][sr+112] = w7.y;
        wt[skq+2][sr+112] = w7.z; wt[skq+3][sr+112] = w7.w;
        __syncthreads();
        if (c + 1 < nc) {
            pA += 32; pW0 += 32; pW1 += 32; pW2 += 32; pW3 += 32;
            pW4 += 32; pW5 += 32; pW6 += 32; pW7 += 32;
            af = *(const float4*)pA;
            w0 = *(const float4*)pW0; w1 = *(const float4*)pW1;
            w2 = *(const float4*)pW2; w3 = *(const float4*)pW3;
            w4 = *(const float4*)pW4; w5 = *(const float4*)pW5;
            w6 = *(const float4*)pW6; w7 = *(const float4*)pW7;
        }
#pragma unroll 8
        for (int kk = 0; kk < 32; ++kk) {
            const float4 a = *(const float4*)&at[kk][r4];
            const float4 w = *(const float4*)&wt[kk][h4];
            const float av[4] = {a.x, a.y, a.z, a.w};
            const float wv[4] = {w.x, w.y, w.z, w.w};
#pragma unroll
            for (int i = 0; i < 4; ++i)
#pragma unroll
                for (int j = 0; j < 4; ++j)
                    acc[i][j] = fmaf(av[i], wv[j], acc[i][j]);
        }
    }

    float* op = psum + ((size_t)blockIdx.y * NROWS + r0) * H_;
#pragma unroll
    for (int i = 0; i < 4; ++i) {
        float4 o = {acc[i][0], acc[i][1], acc[i][2], acc[i][3]};
        *(float4*)&op[(size_t)(r4 + i) * H_ + h4] = o;
    }
}

// ------------------------------------------------------------- reduceP ----
// pout[row][h] = exp2(C2 * (sum_s psum[s][row][h] + bias[h]))  == e^(2x)
__global__ __launch_bounds__(256, 4) void reduceP_kernel(
        const float* __restrict__ psum, const float* __restrict__ bq,
        const float* __restrict__ bk, float* __restrict__ pout) {
    const int tid = threadIdx.x;
    const int r0  = blockIdx.x * 8;
    const float* bias = (r0 < NQR) ? bq : bk;
    const int row = tid >> 5, hq = (tid & 31) * 4;
    float4 s = *(const float4*)&bias[hq];
#pragma unroll
    for (int sp = 0; sp < 4; ++sp) {
        float4 v = *(const float4*)&psum[((size_t)sp * NROWS + r0 + row) * H_ + hq];
        s.x += v.x; s.y += v.y; s.z += v.z; s.w += v.w;
    }
    float4 o = {fexp2(s.x * C2_), fexp2(s.y * C2_),
                fexp2(s.z * C2_), fexp2(s.w * C2_)};
    *(float4*)&pout[(size_t)(r0 + row) * H_ + hq] = o;
}

// -------------------------------------------------------------- scores ----
// Per block: ONE q row (grid 1024 = 4 blocks/CU). Thread owns k=tid and
// k=tid+256. score = bo + sumWo - 2*sum_h Wo_h/(eq_h*ek_h + 1).
// float4 accumulators (4 indep chains); softmax in registers + block reduce.
__global__ __launch_bounds__(256, 4) void scores_kernel(
        const float* __restrict__ qe, const float* __restrict__ ke,
        const float* __restrict__ Wo, const float* __restrict__ bo,
        float* __restrict__ out_attn) {
    __shared__ float qs[H_];
    __shared__ float w2[H_];
    __shared__ float red[8];

    const int tid  = threadIdx.x;
    const int b    = blockIdx.y;
    const int q    = blockIdx.x;
    const int lane = tid & 63;
    const int w    = tid >> 6;

    if (tid < 128) qs[tid] = qe[(size_t)(b * TQ_ + q) * H_ + tid];
    else           w2[tid - 128] = Wo[tid - 128] * -2.0f;
    __syncthreads();

    float sw = w2[lane] + w2[lane + 64];
#pragma unroll
    for (int m = 1; m < 64; m <<= 1) sw += __shfl_xor(sw, m);
    const float sbase = bo[0] - 0.5f * sw;

    const float4* ke0 = (const float4*)&ke[(size_t)(b * TK_ + tid      ) * H_];
    const float4* ke1 = (const float4*)&ke[(size_t)(b * TK_ + tid + 256) * H_];
    float4 a0 = {0.f,0.f,0.f,0.f}, a1 = {0.f,0.f,0.f,0.f};
#pragma unroll 4
    for (int hb = 0; hb < 32; ++hb) {
        const float4 e0 = ke0[hb];
        const float4 e1 = ke1[hb];
        const float4 wv = *(const float4*)&w2[hb * 4];
        const float4 qv = *(const float4*)&qs[hb * 4];
        a0.x = fmaf(wv.x, frcp(fmaf(qv.x, e0.x, 1.f)), a0.x);
        a0.y = fmaf(wv.y, frcp(fmaf(qv.y, e0.y, 1.f)), a0.y);
        a0.z = fmaf(wv.z, frcp(fmaf(qv.z, e0.z, 1.f)), a0.z);
        a0.w = fmaf(wv.w, frcp(fmaf(qv.w, e0.w, 1.f)), a0.w);
        a1.x = fmaf(wv.x, frcp(fmaf(qv.x, e1.x, 1.f)), a1.x);
        a1.y = fmaf(wv.y, frcp(fmaf(qv.y, e1.y, 1.f)), a1.y);
        a1.z = fmaf(wv.z, frcp(fmaf(qv.z, e1.z, 1.f)), a1.z);
        a1.w = fmaf(wv.w, frcp(fmaf(qv.w, e1.w, 1.f)), a1.w);
    }
    const float s0 = (a0.x + a0.y) + (a0.z + a0.w) + sbase;
    const float s1 = (a1.x + a1.y) + (a1.z + a1.w) + sbase;

    // block softmax over 512 scores (2 per thread, in registers)
    float mx = fmaxf(s0, s1);
#pragma unroll
    for (int m = 1; m < 64; m <<= 1) mx = fmaxf(mx, __shfl_xor(mx, m));
    if (lane == 0) red[w] = mx;
    __syncthreads();
    mx = fmaxf(fmaxf(red[0], red[1]), fmaxf(red[2], red[3]));

    const float e0 = fexp2((s0 - mx) * L2E_);
    const float e1 = fexp2((s1 - mx) * L2E_);
    float sum = e0 + e1;
#pragma unroll
    for (int m = 1; m < 64; m <<= 1) sum += __shfl_xor(sum, m);
    if (lane == 0) red[4 + w] = sum;
    __syncthreads();
    sum = (red[4] + red[5]) + (red[6] + red[7]);
    const float inv = frcp(sum);

    float* op = &out_attn[(size_t)(b * TQ_ + q) * TK_];
    op[tid]       = e0 * inv;
    op[tid + 256] = e1 * inv;
}

// ------------------------------------------------------------- context ----
// psumC[z][b,q,v] = sum_{k in z-chunk} attn[b,q,k] * V[b,k,v]  (r10 form)
__global__ __launch_bounds__(128, 4) void context_kernel(
        const float* __restrict__ attn, const float* __restrict__ values,
        float* __restrict__ psumC) {
    __shared__ float at[32][18];    // [kk][q], 16 q
    __shared__ float vt[32][68];    // [kk][v], 64 v

    const int tid = threadIdx.x;
    const int r0  = blockIdx.x * 16;         // global q row (over B*TQ)
    const int b   = r0 >> 7;
    const int v0  = blockIdx.y * 64;
    const int kb0 = blockIdx.z * 128;

    const int q2 = (tid >> 4) * 2;           // 2 q
    const int v4 = (tid & 15) * 4;           // 4 v
    const int ar  = tid >> 3;                // attn stage row 0..15
    const int akq = (tid & 7) * 4;
    const int vr  = tid >> 4;                // values stage row 0..7 (+8p)
    const int vq  = (tid & 15) * 4;

    const float* pAt = attn + (size_t)(r0 + ar) * TK_ + kb0 + akq;
    const float* pV0 = values + (size_t)(b * TK_ + kb0 + vr     ) * NV_ + v0 + vq;
    const float* pV1 = values + (size_t)(b * TK_ + kb0 + vr +  8) * NV_ + v0 + vq;
    const float* pV2 = values + (size_t)(b * TK_ + kb0 + vr + 16) * NV_ + v0 + vq;
    const float* pV3 = values + (size_t)(b * TK_ + kb0 + vr + 24) * NV_ + v0 + vq;

    float4 af  = *(const float4*)pAt;
    float4 vf0 = *(const float4*)pV0;
    float4 vf1 = *(const float4*)pV1;
    float4 vf2 = *(const float4*)pV2;
    float4 vf3 = *(const float4*)pV3;

    float acc[2][4] = {{0.f,0.f,0.f,0.f},{0.f,0.f,0.f,0.f}};

    for (int c = 0; c < 4; ++c) {
        __syncthreads();
        at[akq+0][ar] = af.x; at[akq+1][ar] = af.y;
        at[akq+2][ar] = af.z; at[akq+3][ar] = af.w;
        *(float4*)&vt[vr     ][vq] = vf0;
        *(float4*)&vt[vr +  8][vq] = vf1;
        *(float4*)&vt[vr + 16][vq] = vf2;
        *(float4*)&vt[vr + 24][vq] = vf3;
        __syncthreads();
        if (c + 1 < 4) {
            pAt += 32; pV0 += 32 * NV_; pV1 += 32 * NV_;
            pV2 += 32 * NV_; pV3 += 32 * NV_;
            af  = *(const float4*)pAt;
            vf0 = *(const float4*)pV0; vf1 = *(const float4*)pV1;
            vf2 = *(const float4*)pV2; vf3 = *(const float4*)pV3;
        }
#pragma unroll 8
        for (int kk = 0; kk < 32; ++kk) {
            const float2 a = *(const float2*)&at[kk][q2];
            const float4 v = *(const float4*)&vt[kk][v4];
            acc[0][0] = fmaf(a.x, v.x, acc[0][0]);
            acc[0][1] = fmaf(a.x, v.y, acc[0][1]);
            acc[0][2] = fmaf(a.x, v.z, acc[0][2]);
            acc[0][3] = fmaf(a.x, v.w, acc[0][3]);
            acc[1][0] = fmaf(a.y, v.x, acc[1][0]);
            acc[1][1] = fmaf(a.y, v.y, acc[1][1]);
            acc[1][2] = fmaf(a.y, v.z, acc[1][2]);
            acc[1][3] = fmaf(a.y, v.w, acc[1][3]);
        }
    }

    float* op = psumC + (size_t)blockIdx.z * CTXN + (size_t)r0 * NV_ + v0;
#pragma unroll
    for (int i = 0; i < 2; ++i) {
        float4 o = {acc[i][0], acc[i][1], acc[i][2], acc[i][3]};
        *(float4*)&op[(size_t)(q2 + i) * NV_ + v4] = o;
    }
}

// ------------------------------------------------------------- reduceC ----
// out_ctx[i] = sum_z psumC[z][i]
__global__ __launch_bounds__(256, 4) void reduceC_kernel(
        const float* __restrict__ psumC, float* __restrict__ outc) {
    const size_t i = ((size_t)blockIdx.x * 256 + threadIdx.x) * 4;
    float4 s = *(const float4*)&psumC[i];
#pragma unroll
    for (int z = 1; z < 4; ++z) {
        float4 v = *(const float4*)&psumC[(size_t)z * CTXN + i];
        s.x += v.x; s.y += v.y; s.z += v.z; s.w += v.w;
    }
    *(float4*)&outc[i] = s;
}

// -------------------------------------------------------------- launch ----
extern "C" void kernel_launch(void* const* d_in, const int* in_sizes, int n_in,
                              void* d_out, int out_size, void* d_ws, size_t ws_size,
                              hipStream_t stream) {
    const float* query  = (const float*)d_in[0];
    const float* keys   = (const float*)d_in[1];
    const float* values = (const float*)d_in[2];
    const float* Wq     = (const float*)d_in[3];
    const float* bq     = (const float*)d_in[4];
    const float* Wk     = (const float*)d_in[5];
    const float* bk     = (const float*)d_in[6];
    const float* Wo     = (const float*)d_in[7];
    const float* bo     = (const float*)d_in[8];

    float* out_ctx  = (float*)d_out;                 // B*TQ*NV
    float* out_attn = out_ctx + B_ * TQ_ * NV_;      // B*TQ*TK
    float* pout  = (float*)d_ws;                     // NROWS*H (qe,ke E-values)
    float* qe    = pout;
    float* ke    = pout + (size_t)NQR * H_;
    float* psumP = pout + (size_t)NROWS * H_;        // 4*NROWS*H
    float* psumC = psumP + (size_t)4 * NROWS * H_;   // 4*CTXN

    proj_kernel<<<dim3(NROWS / 16, 4), 128, 0, stream>>>(
        query, keys, Wq, Wk, psumP, NIN_ / 4);
    reduceP_kernel<<<NROWS / 8, 256, 0, stream>>>(psumP, bq, bk, pout);
    scores_kernel<<<dim3(TQ_, B_), 256, 0, stream>>>(qe, ke, Wo, bo, out_attn);
    context_kernel<<<dim3(NQR / 16, NV_ / 64, 4), 128, 0, stream>>>(
        out_attn, values, psumC);
    reduceC_kernel<<<CTXN / 1024, 256, 0, stream>>>(psumC, out_ctx);
}

// Round 18
// 60.623 us; speedup vs baseline: 1.2711x; 1.2711x over previous
//
#include <hip/hip_runtime.h>

// Bahdanau additive attention, f32, 5 kernels.
// = r16 (63.5us best) with ONE change: reduceP emits k E-values TRANSPOSED
// keT[b][h][k] so scores' inner loop is fully coalesced (float4 of 4 k's)
// with scalar q/w broadcasts, replacing 3 LDS-b128 + strided global loads.
// B=8, TQ=128, TK=512, NIN=512, H=128, NV=512.

#define B_    8
#define TQ_   128
#define TK_   512
#define NIN_  512
#define H_    128
#define NV_   512
#define NQR   (B_*TQ_)           // 1024 query rows
#define NROWS (NQR + B_*TK_)     // 5120 projected rows
#define CTXN  (B_*TQ_*NV_)       // 524288 context elems

#define C2_   2.8853900817779268f   // 2*log2(e)
#define L2E_  1.4426950408889634f

__device__ __forceinline__ float fexp2(float x){ return __builtin_amdgcn_exp2f(x); }
__device__ __forceinline__ float frcp (float x){ return __builtin_amdgcn_rcpf(x); }

// ---------------------------------------------------------------- proj ----
// psum[s][row][h] = A[row, ks:ke) . W[h, ks:ke)   (r10/r16 form, unchanged)
__global__ __launch_bounds__(256, 5) void proj_kernel(
        const float* __restrict__ query, const float* __restrict__ keys,
        const float* __restrict__ Wq, const float* __restrict__ Wk,
        float* __restrict__ psum, int kper) {
    __shared__ float at[32][18];     // [kk][row], 16 rows
    __shared__ float wt[32][132];    // [kk][h], 128 h
    const int tid = threadIdx.x;
    const int r0  = blockIdx.x * 16;
    const float* in; const float* W;
    if (r0 < NQR) { in = query + (size_t)r0 * NIN_;         W = Wq; }
    else          { in = keys  + (size_t)(r0 - NQR) * NIN_; W = Wk; }

    const int r2 = (tid >> 5) * 2;       // 2 rows
    const int h4 = (tid & 31) * 4;       // 4 h
    const int ar  = tid >> 4;            // A-stage row 0..15
    const int ak2 = (tid & 15) * 2;      // A-stage k pair
    const int wr  = tid >> 3;            // W-stage h 0..31 (+32p)
    const int wkq = (tid & 7) * 4;       // W-stage k quad
    const int kb0 = blockIdx.y * kper;
    const int nc  = kper >> 5;

    const float* pA  = in + (size_t)ar * NIN_ + kb0 + ak2;
    const float* pW0 = W + (size_t)(wr     ) * NIN_ + kb0 + wkq;
    const float* pW1 = W + (size_t)(wr + 32) * NIN_ + kb0 + wkq;
    const float* pW2 = W + (size_t)(wr + 64) * NIN_ + kb0 + wkq;
    const float* pW3 = W + (size_t)(wr + 96) * NIN_ + kb0 + wkq;

    float2 af = *(const float2*)pA;
    float4 w0 = *(const float4*)pW0, w1 = *(const float4*)pW1;
    float4 w2 = *(const float4*)pW2, w3 = *(const float4*)pW3;

    float acc[2][4] = {{0.f,0.f,0.f,0.f},{0.f,0.f,0.f,0.f}};

    for (int c = 0; c < nc; ++c) {
        __syncthreads();
        at[ak2+0][ar] = af.x; at[ak2+1][ar] = af.y;
        wt[wkq+0][wr   ] = w0.x; wt[wkq+1][wr   ] = w0.y;
        wt[wkq+2][wr   ] = w0.z; wt[wkq+3][wr   ] = w0.w;
        wt[wkq+0][wr+32] = w1.x; wt[wkq+1][wr+32] = w1.y;
        wt[wkq+2][wr+32] = w1.z; wt[wkq+3][wr+32] = w1.w;
        wt[wkq+0][wr+64] = w2.x; wt[wkq+1][wr+64] = w2.y;
        wt[wkq+2][wr+64] = w2.z; wt[wkq+3][wr+64] = w2.w;
        wt[wkq+0][wr+96] = w3.x; wt[wkq+1][wr+96] = w3.y;
        wt[wkq+2][wr+96] = w3.z; wt[wkq+3][wr+96] = w3.w;
        __syncthreads();
        if (c + 1 < nc) {
            pA += 32; pW0 += 32; pW1 += 32; pW2 += 32; pW3 += 32;
            af = *(const float2*)pA;
            w0 = *(const float4*)pW0; w1 = *(const float4*)pW1;
            w2 = *(const float4*)pW2; w3 = *(const float4*)pW3;
        }
#pragma unroll 8
        for (int kk = 0; kk < 32; ++kk) {
            const float2 a = *(const float2*)&at[kk][r2];
            const float4 w = *(const float4*)&wt[kk][h4];
            acc[0][0] = fmaf(a.x, w.x, acc[0][0]);
            acc[0][1] = fmaf(a.x, w.y, acc[0][1]);
            acc[0][2] = fmaf(a.x, w.z, acc[0][2]);
            acc[0][3] = fmaf(a.x, w.w, acc[0][3]);
            acc[1][0] = fmaf(a.y, w.x, acc[1][0]);
            acc[1][1] = fmaf(a.y, w.y, acc[1][1]);
            acc[1][2] = fmaf(a.y, w.z, acc[1][2]);
            acc[1][3] = fmaf(a.y, w.w, acc[1][3]);
        }
    }

    float* op = psum + ((size_t)blockIdx.y * NROWS + r0) * H_;
#pragma unroll
    for (int i = 0; i < 2; ++i) {
        float4 o = {acc[i][0], acc[i][1], acc[i][2], acc[i][3]};
        *(float4*)&op[(size_t)(r2 + i) * H_ + h4] = o;
    }
}

// ------------------------------------------------------------- reduceP ----
// Per block: 16 rows. E = exp2(C2*(sum psum + bias)).
// q rows -> qe[row][h] row-major. k rows -> keT[b][h][k] via LDS transpose.
__global__ __launch_bounds__(256, 4) void reduceP_kernel(
        const float* __restrict__ psum, const float* __restrict__ bq,
        const float* __restrict__ bk, float* __restrict__ qe,
        float* __restrict__ keT) {
    __shared__ float lt[128][17];
    const int tid = threadIdx.x;
    const int r0  = blockIdx.x * 16;
    const bool isq = (r0 < NQR);
    const float* bias = isq ? bq : bk;

#pragma unroll
    for (int p = 0; p < 2; ++p) {
        const int j = tid + p * 256;          // 0..511 over [16 rows][32 hq]
        const int row = j >> 5, hq = (j & 31) * 4;
        float4 s = *(const float4*)&bias[hq];
#pragma unroll
        for (int sp = 0; sp < 4; ++sp) {
            const float4 v = *(const float4*)
                &psum[((size_t)sp * NROWS + r0 + row) * H_ + hq];
            s.x += v.x; s.y += v.y; s.z += v.z; s.w += v.w;
        }
        float4 e = {fexp2(s.x * C2_), fexp2(s.y * C2_),
                    fexp2(s.z * C2_), fexp2(s.w * C2_)};
        if (isq) {
            *(float4*)&qe[(size_t)(r0 + row) * H_ + hq] = e;
        } else {
            lt[hq + 0][row] = e.x; lt[hq + 1][row] = e.y;
            lt[hq + 2][row] = e.z; lt[hq + 3][row] = e.w;
        }
    }
    if (!isq) {
        __syncthreads();
        const int b  = (r0 - NQR) >> 9;
        const int k0 = (r0 - NQR) & 511;
#pragma unroll
        for (int p = 0; p < 2; ++p) {
            const int j = tid + p * 256;      // 0..511 over [128 h][4 kq]
            const int h = j >> 2, kq = (j & 3) * 4;
            float4 o = {lt[h][kq], lt[h][kq + 1], lt[h][kq + 2], lt[h][kq + 3]};
            *(float4*)&keT[((size_t)b * H_ + h) * TK_ + k0 + kq] = o;
        }
    }
}

// -------------------------------------------------------------- scores ----
// Per block: batch b, 2 q rows. Thread = (1 q, 4 contiguous k) via keT.
// score = bo + sumWo - 2*sum_h Wo_h/(eq_h*ek_h + 1). Coalesced float4 ke
// loads; q/w are scalar LDS broadcasts; 4 independent acc chains.
__global__ __launch_bounds__(256, 4) void scores_kernel(
        const float* __restrict__ qe, const float* __restrict__ keT,
        const float* __restrict__ Wo, const float* __restrict__ bo,
        float* __restrict__ out_attn) {
    __shared__ float qs[2][H_];     // e^(2q)
    __shared__ float w2[H_];        // -2 * Wo
    __shared__ float sc[2][TK_];

    const int tid = threadIdx.x;
    const int b   = blockIdx.y;
    const int q0  = blockIdx.x * 2;
    const int lane = tid & 63;

    qs[tid >> 7][tid & 127] =
        qe[(size_t)(b * TQ_ + q0 + (tid >> 7)) * H_ + (tid & 127)];
    if (tid < H_) w2[tid] = Wo[tid] * -2.0f;
    __syncthreads();

    float sw = w2[lane] + w2[lane + 64];
#pragma unroll
    for (int m = 1; m < 64; m <<= 1) sw += __shfl_xor(sw, m);
    const float sbase = bo[0] - 0.5f * sw;

    const int k4 = (tid & 127) * 4;        // 4 contiguous k's
    const int qi = tid >> 7;               // q row 0/1
    const float* pk = keT + (size_t)b * H_ * TK_ + k4;
    float a0 = 0.f, a1 = 0.f, a2 = 0.f, a3 = 0.f;
#pragma unroll 4
    for (int h = 0; h < H_; ++h) {
        const float4 ek = *(const float4*)pk;
        pk += TK_;
        const float qv = qs[qi][h];
        const float wv = w2[h];
        a0 = fmaf(wv, frcp(fmaf(qv, ek.x, 1.f)), a0);
        a1 = fmaf(wv, frcp(fmaf(qv, ek.y, 1.f)), a1);
        a2 = fmaf(wv, frcp(fmaf(qv, ek.z, 1.f)), a2);
        a3 = fmaf(wv, frcp(fmaf(qv, ek.w, 1.f)), a3);
    }
    float4 sv = {a0 + sbase, a1 + sbase, a2 + sbase, a3 + sbase};
    *(float4*)&sc[qi][k4] = sv;
    __syncthreads();

    const int w = tid >> 6;
    if (w < 2) {
        float4 sA = *(const float4*)&sc[w][lane * 8];
        float4 sB = *(const float4*)&sc[w][lane * 8 + 4];
        float m = fmaxf(fmaxf(fmaxf(sA.x, sA.y), fmaxf(sA.z, sA.w)),
                        fmaxf(fmaxf(sB.x, sB.y), fmaxf(sB.z, sB.w)));
#pragma unroll
        for (int mk = 1; mk < 64; mk <<= 1) m = fmaxf(m, __shfl_xor(m, mk));
        float4 eA, eB;
        eA.x = fexp2((sA.x - m) * L2E_); eA.y = fexp2((sA.y - m) * L2E_);
        eA.z = fexp2((sA.z - m) * L2E_); eA.w = fexp2((sA.w - m) * L2E_);
        eB.x = fexp2((sB.x - m) * L2E_); eB.y = fexp2((sB.y - m) * L2E_);
        eB.z = fexp2((sB.z - m) * L2E_); eB.w = fexp2((sB.w - m) * L2E_);
        float s = eA.x + eA.y + eA.z + eA.w + eB.x + eB.y + eB.z + eB.w;
#pragma unroll
        for (int mk = 1; mk < 64; mk <<= 1) s += __shfl_xor(s, mk);
        const float inv = frcp(s);
        eA.x *= inv; eA.y *= inv; eA.z *= inv; eA.w *= inv;
        eB.x *= inv; eB.y *= inv; eB.z *= inv; eB.w *= inv;
        float4* op = (float4*)&out_attn[(size_t)(b * TQ_ + q0 + w) * TK_ + lane * 8];
        op[0] = eA; op[1] = eB;
    }
}

// ------------------------------------------------------------- context ----
// psumC[z][b,q,v] = sum_{k in z-chunk} attn[b,q,k] * V[b,k,v]  (r10 form)
__global__ __launch_bounds__(128, 4) void context_kernel(
        const float* __restrict__ attn, const float* __restrict__ values,
        float* __restrict__ psumC) {
    __shared__ float at[32][18];    // [kk][q], 16 q
    __shared__ float vt[32][68];    // [kk][v], 64 v

    const int tid = threadIdx.x;
    const int r0  = blockIdx.x * 16;         // global q row (over B*TQ)
    const int b   = r0 >> 7;
    const int v0  = blockIdx.y * 64;
    const int kb0 = blockIdx.z * 128;

    const int q2 = (tid >> 4) * 2;           // 2 q
    const int v4 = (tid & 15) * 4;           // 4 v
    const int ar  = tid >> 3;                // attn stage row 0..15
    const int akq = (tid & 7) * 4;
    const int vr  = tid >> 4;                // values stage row 0..7 (+8p)
    const int vq  = (tid & 15) * 4;

    const float* pAt = attn + (size_t)(r0 + ar) * TK_ + kb0 + akq;
    const float* pV0 = values + (size_t)(b * TK_ + kb0 + vr     ) * NV_ + v0 + vq;
    const float* pV1 = values + (size_t)(b * TK_ + kb0 + vr +  8) * NV_ + v0 + vq;
    const float* pV2 = values + (size_t)(b * TK_ + kb0 + vr + 16) * NV_ + v0 + vq;
    const float* pV3 = values + (size_t)(b * TK_ + kb0 + vr + 24) * NV_ + v0 + vq;

    float4 af  = *(const float4*)pAt;
    float4 vf0 = *(const float4*)pV0;
    float4 vf1 = *(const float4*)pV1;
    float4 vf2 = *(const float4*)pV2;
    float4 vf3 = *(const float4*)pV3;

    float acc[2][4] = {{0.f,0.f,0.f,0.f},{0.f,0.f,0.f,0.f}};

    for (int c = 0; c < 4; ++c) {
        __syncthreads();
        at[akq+0][ar] = af.x; at[akq+1][ar] = af.y;
        at[akq+2][ar] = af.z; at[akq+3][ar] = af.w;
        *(float4*)&vt[vr     ][vq] = vf0;
        *(float4*)&vt[vr +  8][vq] = vf1;
        *(float4*)&vt[vr + 16][vq] = vf2;
        *(float4*)&vt[vr + 24][vq] = vf3;
        __syncthreads();
        if (c + 1 < 4) {
            pAt += 32; pV0 += 32 * NV_; pV1 += 32 * NV_;
            pV2 += 32 * NV_; pV3 += 32 * NV_;
            af  = *(const float4*)pAt;
            vf0 = *(const float4*)pV0; vf1 = *(const float4*)pV1;
            vf2 = *(const float4*)pV2; vf3 = *(const float4*)pV3;
        }
#pragma unroll 8
        for (int kk = 0; kk < 32; ++kk) {
            const float2 a = *(const float2*)&at[kk][q2];
            const float4 v = *(const float4*)&vt[kk][v4];
            acc[0][0] = fmaf(a.x, v.x, acc[0][0]);
            acc[0][1] = fmaf(a.x, v.y, acc[0][1]);
            acc[0][2] = fmaf(a.x, v.z, acc[0][2]);
            acc[0][3] = fmaf(a.x, v.w, acc[0][3]);
            acc[1][0] = fmaf(a.y, v.x, acc[1][0]);
            acc[1][1] = fmaf(a.y, v.y, acc[1][1]);
            acc[1][2] = fmaf(a.y, v.z, acc[1][2]);
            acc[1][3] = fmaf(a.y, v.w, acc[1][3]);
        }
    }

    float* op = psumC + (size_t)blockIdx.z * CTXN + (size_t)r0 * NV_ + v0;
#pragma unroll
    for (int i = 0; i < 2; ++i) {
        float4 o = {acc[i][0], acc[i][1], acc[i][2], acc[i][3]};
        *(float4*)&op[(size_t)(q2 + i) * NV_ + v4] = o;
    }
}

// ------------------------------------------------------------- reduceC ----
// out_ctx[i] = sum_z psumC[z][i]
__global__ __launch_bounds__(256, 4) void reduceC_kernel(
        const float* __restrict__ psumC, float* __restrict__ outc) {
    const size_t i = ((size_t)blockIdx.x * 256 + threadIdx.x) * 4;
    float4 s = *(const float4*)&psumC[i];
#pragma unroll
    for (int z = 1; z < 4; ++z) {
        float4 v = *(const float4*)&psumC[(size_t)z * CTXN + i];
        s.x += v.x; s.y += v.y; s.z += v.z; s.w += v.w;
    }
    *(float4*)&outc[i] = s;
}

// -------------------------------------------------------------- launch ----
extern "C" void kernel_launch(void* const* d_in, const int* in_sizes, int n_in,
                              void* d_out, int out_size, void* d_ws, size_t ws_size,
                              hipStream_t stream) {
    const float* query  = (const float*)d_in[0];
    const float* keys   = (const float*)d_in[1];
    const float* values = (const float*)d_in[2];
    const float* Wq     = (const float*)d_in[3];
    const float* bq     = (const float*)d_in[4];
    const float* Wk     = (const float*)d_in[5];
    const float* bk     = (const float*)d_in[6];
    const float* Wo     = (const float*)d_in[7];
    const float* bo     = (const float*)d_in[8];

    float* out_ctx  = (float*)d_out;                 // B*TQ*NV
    float* out_attn = out_ctx + B_ * TQ_ * NV_;      // B*TQ*TK
    float* pout  = (float*)d_ws;                     // qe + keT (E-values)
    float* qe    = pout;                             // NQR*H
    float* keT   = pout + (size_t)NQR * H_;          // B*H*TK
    float* psumP = pout + (size_t)NROWS * H_;        // 4*NROWS*H
    float* psumC = psumP + (size_t)4 * NROWS * H_;   // 4*CTXN

    proj_kernel<<<dim3(NROWS / 16, 4), 256, 0, stream>>>(
        query, keys, Wq, Wk, psumP, NIN_ / 4);
    reduceP_kernel<<<NROWS / 16, 256, 0, stream>>>(psumP, bq, bk, qe, keT);
    scores_kernel<<<dim3(TQ_ / 2, B_), 256, 0, stream>>>(qe, keT, Wo, bo, out_attn);
    context_kernel<<<dim3(NQR / 16, NV_ / 64, 4), 128, 0, stream>>>(
        out_attn, values, psumC);
    reduceC_kernel<<<CTXN / 1024, 256, 0, stream>>>(psumC, out_ctx);
}